// Round 1
// baseline (2299.559 us; speedup 1.0000x reference)
//
#include <hip/hip_runtime.h>
#include <hip/hip_bf16.h>

typedef __attribute__((ext_vector_type(8))) short short8;
typedef __attribute__((ext_vector_type(4))) float floatx4;

#define NNODES 40000
#define CH 128
#define NCLS 40
#define LDK 136   // 128 + 8 pad (bf16 elems) -> row stride 272 B, 16B-aligned

__device__ __forceinline__ unsigned short f2bf(float f) {
    union { float f; unsigned int u; } a; a.f = f;
    unsigned int r = a.u + 0x7FFFu + ((a.u >> 16) & 1u);
    return (unsigned short)(r >> 16);
}

// Convert the 4 hidden 128x128 weights + final 128x40 weight into
// transposed bf16 [out_ch][in_ch] so GEMM B-fragments are contiguous.
// Final weight padded to 48 output cols (rows 40..47 zero).
__global__ void prep_weights(const float* __restrict__ w1a, const float* __restrict__ w1b,
                             const float* __restrict__ w2a, const float* __restrict__ w2b,
                             const float* __restrict__ wlin, unsigned short* __restrict__ wt) {
    int tid = blockIdx.x * blockDim.x + threadIdx.x;
    const int M = CH * CH;
    if (tid < 4 * M) {
        int m = tid / M;
        int n = (tid % M) / CH;   // out channel
        int k = tid % CH;         // in channel
        const float* w = (m == 0) ? w1a : (m == 1) ? w1b : (m == 2) ? w2a : w2b;
        wt[tid] = f2bf(w[k * CH + n]);
    } else if (tid < 4 * M + 48 * CH) {
        int t = tid - 4 * M;
        int n = t / CH, k = t % CH;
        wt[tid] = (n < NCLS) ? f2bf(wlin[k * NCLS + n]) : (unsigned short)0;
    }
}

// agg[dst] += x[src] ; one edge handled by 32 threads (float4 each)
__global__ void scatter_add(const float* __restrict__ x, const int* __restrict__ srcv,
                            const int* __restrict__ dstv, float* __restrict__ agg, int E) {
    long long gid = (long long)blockIdx.x * blockDim.x + threadIdx.x;
    int e = (int)(gid >> 5);
    if (e >= E) return;
    int c = ((int)gid & 31) * 4;
    int s = srcv[e], d = dstv[e];
    float4 v = *(const float4*)(x + (long long)s * CH + c);
    float* ap = agg + (long long)d * CH + c;
    atomicAdd(ap + 0, v.x);
    atomicAdd(ap + 1, v.y);
    atomicAdd(ap + 2, v.z);
    atomicAdd(ap + 3, v.w);
}

// out[rows x ncols_out] = act( (in (+agg)) @ wt^T + bias )
// Block: 256 threads = 4 waves; 64 rows x (NTILES*16) cols per block.
// MFMA 16x16x32 bf16; A-frag: row = lane&15, k = (lane>>4)*8+j;
// C/D: col = lane&15, row = (lane>>4)*4 + reg.
template<int NTILES, bool RELU, bool ADDAGG>
__global__ __launch_bounds__(256)
void gemm_kernel(const float* __restrict__ in, const float* __restrict__ agg,
                 const unsigned short* __restrict__ wt, const float* __restrict__ bias,
                 float* __restrict__ out, int ncols_out) {
    __shared__ unsigned short Alds[64 * LDK];
    __shared__ unsigned short Wlds[NTILES * 16 * LDK];
    const int tid = threadIdx.x;
    const long long rowbase = (long long)blockIdx.x * 64;

    // stage A (64 x 128) fp32 -> bf16, optionally fusing + agg
    {
        int c = (tid & 31) * 4;
        for (int r = tid >> 5; r < 64; r += 8) {
            float4 v = *(const float4*)(in + (rowbase + r) * CH + c);
            if (ADDAGG) {
                float4 g = *(const float4*)(agg + (rowbase + r) * CH + c);
                v.x += g.x; v.y += g.y; v.z += g.z; v.w += g.w;
            }
            union { unsigned short us[4]; uint2 u2; } pk;
            pk.us[0] = f2bf(v.x); pk.us[1] = f2bf(v.y);
            pk.us[2] = f2bf(v.z); pk.us[3] = f2bf(v.w);
            *(uint2*)&Alds[r * LDK + c] = pk.u2;
        }
    }
    // stage W (NTILES*16 x 128) bf16, already transposed/contiguous in ws
    {
        #pragma unroll
        for (int i = 0; i < NTILES; ++i) {
            int chunk = i * 256 + tid;
            int row = chunk >> 4;
            int col = (chunk & 15) * 8;
            *(int4*)&Wlds[row * LDK + col] = *(const int4*)(wt + row * CH + col);
        }
    }
    __syncthreads();

    const int wave = tid >> 6;
    const int lane = tid & 63;
    const int q = lane >> 4;
    const int ln = lane & 15;

    floatx4 acc[NTILES];
    #pragma unroll
    for (int t = 0; t < NTILES; ++t) acc[t] = (floatx4){0.f, 0.f, 0.f, 0.f};

    const int abase = (wave * 16 + ln) * LDK + q * 8;
    #pragma unroll
    for (int ks = 0; ks < 4; ++ks) {
        short8 af = *(const short8*)&Alds[abase + ks * 32];
        #pragma unroll
        for (int t = 0; t < NTILES; ++t) {
            short8 bf = *(const short8*)&Wlds[(t * 16 + ln) * LDK + q * 8 + ks * 32];
            acc[t] = __builtin_amdgcn_mfma_f32_16x16x32_bf16(af, bf, acc[t], 0, 0, 0);
        }
    }

    #pragma unroll
    for (int t = 0; t < NTILES; ++t) {
        int col = t * 16 + ln;
        if (col < ncols_out) {
            float b = bias[col];
            #pragma unroll
            for (int r = 0; r < 4; ++r) {
                long long row = rowbase + wave * 16 + q * 4 + r;
                float v = acc[t][r] + b;
                if (RELU) v = fmaxf(v, 0.f);
                out[row * ncols_out + col] = v;
            }
        }
    }
}

extern "C" void kernel_launch(void* const* d_in, const int* in_sizes, int n_in,
                              void* d_out, int out_size, void* d_ws, size_t ws_size,
                              hipStream_t stream) {
    const float* x    = (const float*)d_in[0];
    const int*   ei   = (const int*)d_in[1];
    const float* w1a  = (const float*)d_in[2];
    const float* b1a  = (const float*)d_in[3];
    const float* w1b  = (const float*)d_in[4];
    const float* b1b  = (const float*)d_in[5];
    const float* w2a  = (const float*)d_in[6];
    const float* b2a  = (const float*)d_in[7];
    const float* w2b  = (const float*)d_in[8];
    const float* b2b  = (const float*)d_in[9];
    const float* wlin = (const float*)d_in[10];
    const float* blin = (const float*)d_in[11];
    const int E = in_sizes[1] / 2;
    const int* srcv = ei;
    const int* dstv = ei + E;

    unsigned short* wt = (unsigned short*)d_ws;           // 71680 bf16 = 143 KB
    float* bufA = (float*)((char*)d_ws + 262144);         // agg / later h2
    float* bufB = bufA + (size_t)NNODES * CH;
    float* bufC = bufB + (size_t)NNODES * CH;
    const size_t BUFB = (size_t)NNODES * CH * sizeof(float);

    const int WT_ELEMS = 4 * CH * CH + 48 * CH;
    prep_weights<<<(WT_ELEMS + 255) / 256, 256, 0, stream>>>(w1a, w1b, w2a, w2b, wlin, wt);

    long long sthr = (long long)E * 32;
    int sblocks = (int)((sthr + 255) / 256);

    // ---- layer 1 ----
    hipMemsetAsync(bufA, 0, BUFB, stream);
    scatter_add<<<sblocks, 256, 0, stream>>>(x, srcv, dstv, bufA, E);
    gemm_kernel<8, true, true ><<<NNODES / 64, 256, 0, stream>>>(x,    bufA,    wt,               b1a, bufB, CH);
    gemm_kernel<8, true, false><<<NNODES / 64, 256, 0, stream>>>(bufB, nullptr, wt + CH * CH,     b1b, bufC, CH);
    // ---- layer 2 ----
    hipMemsetAsync(bufA, 0, BUFB, stream);
    scatter_add<<<sblocks, 256, 0, stream>>>(bufC, srcv, dstv, bufA, E);
    gemm_kernel<8, true, true ><<<NNODES / 64, 256, 0, stream>>>(bufC, bufA,    wt + 2 * CH * CH, b2a, bufB, CH);
    gemm_kernel<8, true, false><<<NNODES / 64, 256, 0, stream>>>(bufB, nullptr, wt + 3 * CH * CH, b2b, bufA, CH);
    // ---- final linear ----
    gemm_kernel<3, false, false><<<NNODES / 64, 256, 0, stream>>>(bufA, nullptr, wt + 4 * CH * CH, blin, (float*)d_out, NCLS);
}

// Round 2
// 407.778 us; speedup vs baseline: 5.6392x; 5.6392x over previous
//
#include <hip/hip_runtime.h>
#include <hip/hip_bf16.h>

typedef __attribute__((ext_vector_type(8))) short short8;
typedef __attribute__((ext_vector_type(4))) float floatx4;

#define NNODES 40000
#define CH 128
#define NCLS 40
#define LDK 136   // 128 + 8 pad (bf16 elems) -> row stride 272 B, 16B-aligned

__device__ __forceinline__ unsigned short f2bf(float f) {
    union { float f; unsigned int u; } a; a.f = f;
    unsigned int r = a.u + 0x7FFFu + ((a.u >> 16) & 1u);
    return (unsigned short)(r >> 16);
}

// Convert the 4 hidden 128x128 weights + final 128x40 weight into
// transposed bf16 [out_ch][in_ch] so GEMM B-fragments are contiguous.
__global__ void prep_weights(const float* __restrict__ w1a, const float* __restrict__ w1b,
                             const float* __restrict__ w2a, const float* __restrict__ w2b,
                             const float* __restrict__ wlin, unsigned short* __restrict__ wt) {
    int tid = blockIdx.x * blockDim.x + threadIdx.x;
    const int M = CH * CH;
    if (tid < 4 * M) {
        int m = tid / M;
        int n = (tid % M) / CH;   // out channel
        int k = tid % CH;         // in channel
        const float* w = (m == 0) ? w1a : (m == 1) ? w1b : (m == 2) ? w2a : w2b;
        wt[tid] = f2bf(w[k * CH + n]);
    } else if (tid < 4 * M + 48 * CH) {
        int t = tid - 4 * M;
        int n = t / CH, k = t % CH;
        wt[tid] = (n < NCLS) ? f2bf(wlin[k * NCLS + n]) : (unsigned short)0;
    }
}

// ---------------- CSR build (once per call; no fp atomics in hot path) ----
__global__ void count_deg(const int* __restrict__ dstv, int* __restrict__ deg, int E) {
    int e = blockIdx.x * blockDim.x + threadIdx.x;
    if (e < E) atomicAdd(&deg[dstv[e]], 1);
}

// Single-block exclusive scan over 40000 degrees -> rowptr (and cursor copy).
__global__ __launch_bounds__(256) void scan_deg(const int* __restrict__ deg,
                                                int* __restrict__ rowptr,
                                                int* __restrict__ cursor) {
    __shared__ int partial[256];
    const int tid = threadIdx.x;
    const int CHUNK = (NNODES + 255) / 256;   // 157
    const int base = tid * CHUNK;
    int sum = 0;
    for (int i = 0; i < CHUNK; ++i) {
        int idx = base + i;
        if (idx < NNODES) sum += deg[idx];
    }
    partial[tid] = sum;
    __syncthreads();
    for (int off = 1; off < 256; off <<= 1) {
        int t = 0;
        if (tid >= off) t = partial[tid - off];
        __syncthreads();
        if (tid >= off) partial[tid] += t;
        __syncthreads();
    }
    int run = partial[tid] - sum;   // exclusive offset for this chunk
    for (int i = 0; i < CHUNK; ++i) {
        int idx = base + i;
        if (idx < NNODES) {
            rowptr[idx] = run;
            cursor[idx] = run;
            run += deg[idx];
        }
    }
    if (tid == 255) rowptr[NNODES] = run;  // == E
}

__global__ void fill_csr(const int* __restrict__ srcv, const int* __restrict__ dstv,
                         int* __restrict__ cursor, int* __restrict__ srclist, int E) {
    int e = blockIdx.x * blockDim.x + threadIdx.x;
    if (e >= E) return;
    int pos = atomicAdd(&cursor[dstv[e]], 1);
    srclist[pos] = srcv[e];
}

// out[node] = x[node] + sum_{e in CSR(node)} x[srclist[e]]   (fp32)
// One wave per node; half-wave 0 takes even edges, half-wave 1 odd edges;
// each lane owns 4 channels (float4). Halves combined via shfl(lane^32).
__global__ __launch_bounds__(256) void gather_sum(const float* __restrict__ x,
                                                  const int* __restrict__ rowptr,
                                                  const int* __restrict__ srclist,
                                                  float* __restrict__ out) {
    int node = blockIdx.x * 4 + (threadIdx.x >> 6);
    if (node >= NNODES) return;
    const int lane = threadIdx.x & 63;
    const int half = lane >> 5;
    const int c = (lane & 31) * 4;
    const int start = rowptr[node];
    const int end = rowptr[node + 1];

    float4 acc;
    if (half == 0) {
        acc = *(const float4*)(x + (long long)node * CH + c);  // self term (eps=0)
    } else {
        acc = make_float4(0.f, 0.f, 0.f, 0.f);
    }
    for (int i = start + half; i < end; i += 2) {
        int s = srclist[i];
        float4 v = *(const float4*)(x + (long long)s * CH + c);
        acc.x += v.x; acc.y += v.y; acc.z += v.z; acc.w += v.w;
    }
    // combine the two halves
    int other = lane ^ 32;
    acc.x += __shfl(acc.x, other);
    acc.y += __shfl(acc.y, other);
    acc.z += __shfl(acc.z, other);
    acc.w += __shfl(acc.w, other);
    if (half == 0) *(float4*)(out + (long long)node * CH + c) = acc;
}

// out[rows x ncols_out] = act( in @ wt^T + bias )
// Block: 256 threads = 4 waves; 64 rows x (NTILES*16) cols per block.
template<int NTILES, bool RELU>
__global__ __launch_bounds__(256)
void gemm_kernel(const float* __restrict__ in,
                 const unsigned short* __restrict__ wt, const float* __restrict__ bias,
                 float* __restrict__ out, int ncols_out) {
    __shared__ unsigned short Alds[64 * LDK];
    __shared__ unsigned short Wlds[NTILES * 16 * LDK];
    const int tid = threadIdx.x;
    const long long rowbase = (long long)blockIdx.x * 64;

    // stage A (64 x 128) fp32 -> bf16
    {
        int c = (tid & 31) * 4;
        for (int r = tid >> 5; r < 64; r += 8) {
            float4 v = *(const float4*)(in + (rowbase + r) * CH + c);
            union { unsigned short us[4]; uint2 u2; } pk;
            pk.us[0] = f2bf(v.x); pk.us[1] = f2bf(v.y);
            pk.us[2] = f2bf(v.z); pk.us[3] = f2bf(v.w);
            *(uint2*)&Alds[r * LDK + c] = pk.u2;
        }
    }
    // stage W (NTILES*16 x 128) bf16, already transposed/contiguous in ws
    {
        #pragma unroll
        for (int i = 0; i < NTILES; ++i) {
            int chunk = i * 256 + tid;
            int row = chunk >> 4;
            int col = (chunk & 15) * 8;
            *(int4*)&Wlds[row * LDK + col] = *(const int4*)(wt + row * CH + col);
        }
    }
    __syncthreads();

    const int wave = tid >> 6;
    const int lane = tid & 63;
    const int q = lane >> 4;
    const int ln = lane & 15;

    floatx4 acc[NTILES];
    #pragma unroll
    for (int t = 0; t < NTILES; ++t) acc[t] = (floatx4){0.f, 0.f, 0.f, 0.f};

    const int abase = (wave * 16 + ln) * LDK + q * 8;
    #pragma unroll
    for (int ks = 0; ks < 4; ++ks) {
        short8 af = *(const short8*)&Alds[abase + ks * 32];
        #pragma unroll
        for (int t = 0; t < NTILES; ++t) {
            short8 bf = *(const short8*)&Wlds[(t * 16 + ln) * LDK + q * 8 + ks * 32];
            acc[t] = __builtin_amdgcn_mfma_f32_16x16x32_bf16(af, bf, acc[t], 0, 0, 0);
        }
    }

    #pragma unroll
    for (int t = 0; t < NTILES; ++t) {
        int col = t * 16 + ln;
        if (col < ncols_out) {
            float b = bias[col];
            #pragma unroll
            for (int r = 0; r < 4; ++r) {
                long long row = rowbase + wave * 16 + q * 4 + r;
                float v = acc[t][r] + b;
                if (RELU) v = fmaxf(v, 0.f);
                out[row * ncols_out + col] = v;
            }
        }
    }
}

extern "C" void kernel_launch(void* const* d_in, const int* in_sizes, int n_in,
                              void* d_out, int out_size, void* d_ws, size_t ws_size,
                              hipStream_t stream) {
    const float* x    = (const float*)d_in[0];
    const int*   ei   = (const int*)d_in[1];
    const float* w1a  = (const float*)d_in[2];
    const float* b1a  = (const float*)d_in[3];
    const float* w1b  = (const float*)d_in[4];
    const float* b1b  = (const float*)d_in[5];
    const float* w2a  = (const float*)d_in[6];
    const float* b2a  = (const float*)d_in[7];
    const float* w2b  = (const float*)d_in[8];
    const float* b2b  = (const float*)d_in[9];
    const float* wlin = (const float*)d_in[10];
    const float* blin = (const float*)d_in[11];
    const int E = in_sizes[1] / 2;
    const int* srcv = ei;
    const int* dstv = ei + E;

    const size_t NODEF = (size_t)NNODES * CH;            // 5.12M floats
    unsigned short* wt = (unsigned short*)d_ws;          // 143 KB, pad to 256 KB
    float* bufA = (float*)((char*)d_ws + 262144);
    float* bufB = bufA + NODEF;
    float* bufC = bufB + NODEF;
    // deg/cursor alias bufC (only live during CSR build, before bufC's first GEMM write)
    int* deg    = (int*)bufC;
    int* cursor = deg + NNODES;
    // persistent CSR arrays after bufC
    int* rowptr  = (int*)(bufC + NODEF);                 // NNODES+1
    int* srclist = rowptr + (NNODES + 1);                // E

    const int WT_ELEMS = 4 * CH * CH + 48 * CH;
    prep_weights<<<(WT_ELEMS + 255) / 256, 256, 0, stream>>>(w1a, w1b, w2a, w2b, wlin, wt);

    // ---- CSR build ----
    hipMemsetAsync(deg, 0, NNODES * sizeof(int), stream);
    count_deg<<<(E + 255) / 256, 256, 0, stream>>>(dstv, deg, E);
    scan_deg<<<1, 256, 0, stream>>>(deg, rowptr, cursor);
    fill_csr<<<(E + 255) / 256, 256, 0, stream>>>(srcv, dstv, cursor, srclist, E);

    const int GBLOCKS = (NNODES + 3) / 4;

    // ---- layer 1 ----
    gather_sum<<<GBLOCKS, 256, 0, stream>>>(x, rowptr, srclist, bufA);          // bufA = x + agg(x)
    gemm_kernel<8, true ><<<NNODES / 64, 256, 0, stream>>>(bufA, wt,              b1a, bufB, CH);
    gemm_kernel<8, true ><<<NNODES / 64, 256, 0, stream>>>(bufB, wt + CH * CH,    b1b, bufC, CH);  // bufC = h1
    // ---- layer 2 ----
    gather_sum<<<GBLOCKS, 256, 0, stream>>>(bufC, rowptr, srclist, bufA);       // bufA = h1 + agg(h1)
    gemm_kernel<8, true ><<<NNODES / 64, 256, 0, stream>>>(bufA, wt + 2 * CH * CH, b2a, bufB, CH);
    gemm_kernel<8, true ><<<NNODES / 64, 256, 0, stream>>>(bufB, wt + 3 * CH * CH, b2b, bufC, CH);
    // ---- final linear ----
    gemm_kernel<3, false><<<NNODES / 64, 256, 0, stream>>>(bufC, wt + 4 * CH * CH, blin, (float*)d_out, NCLS);
}

// Round 3
// 303.226 us; speedup vs baseline: 7.5836x; 1.3448x over previous
//
#include <hip/hip_runtime.h>
#include <hip/hip_bf16.h>

typedef __attribute__((ext_vector_type(8))) short short8;
typedef __attribute__((ext_vector_type(4))) float floatx4;

#define NNODES 40000
#define CH 128
#define NCLS 40
#define LDK 136   // 128 + 8 pad (bf16 elems) -> row stride 272 B, 16B-aligned

#define SCAN_BLK 40           // ceil(40000/1024)
#define SCAN_ELEMS 1024       // elems per scan block (256 thr x int4)

__device__ __forceinline__ unsigned short f2bf(float f) {
    union { float f; unsigned int u; } a; a.f = f;
    unsigned int r = a.u + 0x7FFFu + ((a.u >> 16) & 1u);
    return (unsigned short)(r >> 16);
}

// Convert the 4 hidden 128x128 weights + final 128x40 weight into
// transposed bf16 [out_ch][in_ch] so GEMM B-fragments are contiguous.
__global__ void prep_weights(const float* __restrict__ w1a, const float* __restrict__ w1b,
                             const float* __restrict__ w2a, const float* __restrict__ w2b,
                             const float* __restrict__ wlin, unsigned short* __restrict__ wt) {
    int tid = blockIdx.x * blockDim.x + threadIdx.x;
    const int M = CH * CH;
    if (tid < 4 * M) {
        int m = tid / M;
        int n = (tid % M) / CH;   // out channel
        int k = tid % CH;         // in channel
        const float* w = (m == 0) ? w1a : (m == 1) ? w1b : (m == 2) ? w2a : w2b;
        wt[tid] = f2bf(w[k * CH + n]);
    } else if (tid < 4 * M + 48 * CH) {
        int t = tid - 4 * M;
        int n = t / CH, k = t % CH;
        wt[tid] = (n < NCLS) ? f2bf(wlin[k * NCLS + n]) : (unsigned short)0;
    }
}

// ---------------- CSR build (no fp atomics; parallel 3-kernel scan) -------
__global__ void count_deg(const int* __restrict__ dstv, int* __restrict__ deg, int E) {
    int e = blockIdx.x * blockDim.x + threadIdx.x;
    if (e < E) atomicAdd(&deg[dstv[e]], 1);
}

// Pass 1: per-block local exclusive scan (1024 elems/block) + block totals.
__global__ __launch_bounds__(256) void scan_blocks(const int* __restrict__ deg,
                                                   int* __restrict__ rowptr,
                                                   int* __restrict__ blocksum) {
    __shared__ int wtot[4];
    const int tid = threadIdx.x;
    const int lane = tid & 63;
    const int wave = tid >> 6;
    const int idx = blockIdx.x * SCAN_ELEMS + tid * 4;

    int4 d = make_int4(0, 0, 0, 0);
    if (idx < NNODES) d = *(const int4*)(deg + idx);
    int s = d.x + d.y + d.z + d.w;

    // inclusive wave scan
    int inc = s;
    #pragma unroll
    for (int off = 1; off < 64; off <<= 1) {
        int n = __shfl_up(inc, off);
        if (lane >= off) inc += n;
    }
    if (lane == 63) wtot[wave] = inc;
    __syncthreads();
    int woff = 0;
    #pragma unroll
    for (int w = 0; w < 4; ++w) if (w < wave) woff += wtot[w];

    int excl = woff + inc - s;   // block-local exclusive offset of this thread
    if (idx < NNODES) {
        int4 r;
        r.x = excl;
        r.y = r.x + d.x;
        r.z = r.y + d.y;
        r.w = r.z + d.z;
        *(int4*)(rowptr + idx) = r;
    }
    if (tid == 255) blocksum[blockIdx.x] = woff + inc;   // block total
}

// Pass 2: scan the 40 block sums in one wave.
__global__ __launch_bounds__(64) void scan_tops(const int* __restrict__ blocksum,
                                                int* __restrict__ blockoff,
                                                int* __restrict__ rowptr) {
    const int lane = threadIdx.x;
    int v = (lane < SCAN_BLK) ? blocksum[lane] : 0;
    int inc = v;
    #pragma unroll
    for (int off = 1; off < 64; off <<= 1) {
        int n = __shfl_up(inc, off);
        if (lane >= off) inc += n;
    }
    if (lane < SCAN_BLK) blockoff[lane] = inc - v;   // exclusive
    if (lane == 63) rowptr[NNODES] = inc;            // total == E
}

// Pass 3: add block offsets; emit final rowptr and cursor copy.
__global__ __launch_bounds__(256) void scan_apply(int* __restrict__ rowptr,
                                                  int* __restrict__ cursor,
                                                  const int* __restrict__ blockoff) {
    const int idx = blockIdx.x * SCAN_ELEMS + threadIdx.x * 4;
    if (idx >= NNODES) return;
    const int off = blockoff[blockIdx.x];
    int4 r = *(const int4*)(rowptr + idx);
    r.x += off; r.y += off; r.z += off; r.w += off;
    *(int4*)(rowptr + idx) = r;
    *(int4*)(cursor + idx) = r;
}

__global__ void fill_csr(const int* __restrict__ srcv, const int* __restrict__ dstv,
                         int* __restrict__ cursor, int* __restrict__ srclist, int E) {
    int e = blockIdx.x * blockDim.x + threadIdx.x;
    if (e >= E) return;
    int pos = atomicAdd(&cursor[dstv[e]], 1);
    srclist[pos] = srcv[e];
}

// out[node] = x[node] + sum_{e in CSR(node)} x[srclist[e]]   (fp32)
__global__ __launch_bounds__(256) void gather_sum(const float* __restrict__ x,
                                                  const int* __restrict__ rowptr,
                                                  const int* __restrict__ srclist,
                                                  float* __restrict__ out) {
    int node = blockIdx.x * 4 + (threadIdx.x >> 6);
    if (node >= NNODES) return;
    const int lane = threadIdx.x & 63;
    const int half = lane >> 5;
    const int c = (lane & 31) * 4;
    const int start = rowptr[node];
    const int end = rowptr[node + 1];

    float4 acc;
    if (half == 0) {
        acc = *(const float4*)(x + (long long)node * CH + c);  // self term (eps=0)
    } else {
        acc = make_float4(0.f, 0.f, 0.f, 0.f);
    }
    for (int i = start + half; i < end; i += 2) {
        int s = srclist[i];
        float4 v = *(const float4*)(x + (long long)s * CH + c);
        acc.x += v.x; acc.y += v.y; acc.z += v.z; acc.w += v.w;
    }
    int other = lane ^ 32;
    acc.x += __shfl(acc.x, other);
    acc.y += __shfl(acc.y, other);
    acc.z += __shfl(acc.z, other);
    acc.w += __shfl(acc.w, other);
    if (half == 0) *(float4*)(out + (long long)node * CH + c) = acc;
}

// out[rows x ncols_out] = act( in @ wt^T + bias )
template<int NTILES, bool RELU>
__global__ __launch_bounds__(256)
void gemm_kernel(const float* __restrict__ in,
                 const unsigned short* __restrict__ wt, const float* __restrict__ bias,
                 float* __restrict__ out, int ncols_out) {
    __shared__ unsigned short Alds[64 * LDK];
    __shared__ unsigned short Wlds[NTILES * 16 * LDK];
    const int tid = threadIdx.x;
    const long long rowbase = (long long)blockIdx.x * 64;

    {
        int c = (tid & 31) * 4;
        for (int r = tid >> 5; r < 64; r += 8) {
            float4 v = *(const float4*)(in + (rowbase + r) * CH + c);
            union { unsigned short us[4]; uint2 u2; } pk;
            pk.us[0] = f2bf(v.x); pk.us[1] = f2bf(v.y);
            pk.us[2] = f2bf(v.z); pk.us[3] = f2bf(v.w);
            *(uint2*)&Alds[r * LDK + c] = pk.u2;
        }
    }
    {
        #pragma unroll
        for (int i = 0; i < NTILES; ++i) {
            int chunk = i * 256 + tid;
            int row = chunk >> 4;
            int col = (chunk & 15) * 8;
            *(int4*)&Wlds[row * LDK + col] = *(const int4*)(wt + row * CH + col);
        }
    }
    __syncthreads();

    const int wave = tid >> 6;
    const int lane = tid & 63;
    const int q = lane >> 4;
    const int ln = lane & 15;

    floatx4 acc[NTILES];
    #pragma unroll
    for (int t = 0; t < NTILES; ++t) acc[t] = (floatx4){0.f, 0.f, 0.f, 0.f};

    const int abase = (wave * 16 + ln) * LDK + q * 8;
    #pragma unroll
    for (int ks = 0; ks < 4; ++ks) {
        short8 af = *(const short8*)&Alds[abase + ks * 32];
        #pragma unroll
        for (int t = 0; t < NTILES; ++t) {
            short8 bf = *(const short8*)&Wlds[(t * 16 + ln) * LDK + q * 8 + ks * 32];
            acc[t] = __builtin_amdgcn_mfma_f32_16x16x32_bf16(af, bf, acc[t], 0, 0, 0);
        }
    }

    #pragma unroll
    for (int t = 0; t < NTILES; ++t) {
        int col = t * 16 + ln;
        if (col < ncols_out) {
            float b = bias[col];
            #pragma unroll
            for (int r = 0; r < 4; ++r) {
                long long row = rowbase + wave * 16 + q * 4 + r;
                float v = acc[t][r] + b;
                if (RELU) v = fmaxf(v, 0.f);
                out[row * ncols_out + col] = v;
            }
        }
    }
}

extern "C" void kernel_launch(void* const* d_in, const int* in_sizes, int n_in,
                              void* d_out, int out_size, void* d_ws, size_t ws_size,
                              hipStream_t stream) {
    const float* x    = (const float*)d_in[0];
    const int*   ei   = (const int*)d_in[1];
    const float* w1a  = (const float*)d_in[2];
    const float* b1a  = (const float*)d_in[3];
    const float* w1b  = (const float*)d_in[4];
    const float* b1b  = (const float*)d_in[5];
    const float* w2a  = (const float*)d_in[6];
    const float* b2a  = (const float*)d_in[7];
    const float* w2b  = (const float*)d_in[8];
    const float* b2b  = (const float*)d_in[9];
    const float* wlin = (const float*)d_in[10];
    const float* blin = (const float*)d_in[11];
    const int E = in_sizes[1] / 2;
    const int* srcv = ei;
    const int* dstv = ei + E;

    const size_t NODEF = (size_t)NNODES * CH;            // 5.12M floats
    unsigned short* wt = (unsigned short*)d_ws;          // 143 KB, pad to 256 KB
    float* bufA = (float*)((char*)d_ws + 262144);
    float* bufB = bufA + NODEF;
    float* bufC = bufB + NODEF;
    // deg/cursor alias bufC (only live during CSR build, before bufC's first GEMM write)
    int* deg    = (int*)bufC;
    int* cursor = deg + NNODES;
    // persistent CSR arrays after bufC
    int* rowptr   = (int*)(bufC + NODEF);                // NNODES+1
    int* srclist  = rowptr + (NNODES + 1);               // E
    int* blocksum = srclist + E;                         // SCAN_BLK (pad 64)
    int* blockoff = blocksum + 64;                       // SCAN_BLK

    const int WT_ELEMS = 4 * CH * CH + 48 * CH;
    prep_weights<<<(WT_ELEMS + 255) / 256, 256, 0, stream>>>(w1a, w1b, w2a, w2b, wlin, wt);

    // ---- CSR build ----
    hipMemsetAsync(deg, 0, NNODES * sizeof(int), stream);
    count_deg<<<(E + 255) / 256, 256, 0, stream>>>(dstv, deg, E);
    scan_blocks<<<SCAN_BLK, 256, 0, stream>>>(deg, rowptr, blocksum);
    scan_tops<<<1, 64, 0, stream>>>(blocksum, blockoff, rowptr);
    scan_apply<<<SCAN_BLK, 256, 0, stream>>>(rowptr, cursor, blockoff);
    fill_csr<<<(E + 255) / 256, 256, 0, stream>>>(srcv, dstv, cursor, srclist, E);

    const int GBLOCKS = (NNODES + 3) / 4;

    // ---- layer 1 ----
    gather_sum<<<GBLOCKS, 256, 0, stream>>>(x, rowptr, srclist, bufA);          // bufA = x + agg(x)
    gemm_kernel<8, true ><<<NNODES / 64, 256, 0, stream>>>(bufA, wt,              b1a, bufB, CH);
    gemm_kernel<8, true ><<<NNODES / 64, 256, 0, stream>>>(bufB, wt + CH * CH,    b1b, bufC, CH);  // bufC = h1
    // ---- layer 2 ----
    gather_sum<<<GBLOCKS, 256, 0, stream>>>(bufC, rowptr, srclist, bufA);       // bufA = h1 + agg(h1)
    gemm_kernel<8, true ><<<NNODES / 64, 256, 0, stream>>>(bufA, wt + 2 * CH * CH, b2a, bufB, CH);
    gemm_kernel<8, true ><<<NNODES / 64, 256, 0, stream>>>(bufB, wt + 3 * CH * CH, b2b, bufC, CH);
    // ---- final linear ----
    gemm_kernel<3, false><<<NNODES / 64, 256, 0, stream>>>(bufC, wt + 4 * CH * CH, blin, (float*)d_out, NCLS);
}

// Round 4
// 259.018 us; speedup vs baseline: 8.8780x; 1.1707x over previous
//
#include <hip/hip_runtime.h>
#include <hip/hip_bf16.h>

typedef __attribute__((ext_vector_type(8))) short short8;
typedef __attribute__((ext_vector_type(4))) float floatx4;

#define NNODES 40000
#define CH 128
#define NCLS 40
#define LDK 136   // 128 + 8 pad (bf16 elems) -> row stride 272 B, 16B-aligned

#define SCAN_BLK 40           // ceil(40000/1024)
#define SCAN_ELEMS 1024       // elems per scan block (256 thr x int4)

__device__ __forceinline__ unsigned short f2bf(float f) {
    union { float f; unsigned int u; } a; a.f = f;
    unsigned int r = a.u + 0x7FFFu + ((a.u >> 16) & 1u);
    return (unsigned short)(r >> 16);
}
__device__ __forceinline__ float bflo(unsigned int w) {
    union { unsigned int u; float f; } a; a.u = w << 16; return a.f;
}
__device__ __forceinline__ float bfhi(unsigned int w) {
    union { unsigned int u; float f; } a; a.u = w & 0xffff0000u; return a.f;
}

// Convert the 4 hidden 128x128 weights + final 128x40 weight into
// transposed bf16 [out_ch][in_ch] so GEMM B-fragments are contiguous.
__global__ void prep_weights(const float* __restrict__ w1a, const float* __restrict__ w1b,
                             const float* __restrict__ w2a, const float* __restrict__ w2b,
                             const float* __restrict__ wlin, unsigned short* __restrict__ wt) {
    int tid = blockIdx.x * blockDim.x + threadIdx.x;
    const int M = CH * CH;
    if (tid < 4 * M) {
        int m = tid / M;
        int n = (tid % M) / CH;   // out channel
        int k = tid % CH;         // in channel
        const float* w = (m == 0) ? w1a : (m == 1) ? w1b : (m == 2) ? w2a : w2b;
        wt[tid] = f2bf(w[k * CH + n]);
    } else if (tid < 4 * M + 48 * CH) {
        int t = tid - 4 * M;
        int n = t / CH, k = t % CH;
        wt[tid] = (n < NCLS) ? f2bf(wlin[k * NCLS + n]) : (unsigned short)0;
    }
}

// fp32 -> bf16 bulk convert (x table)
__global__ __launch_bounds__(256) void cvt_bf16(const float* __restrict__ x,
                                                unsigned short* __restrict__ xb, int n4) {
    int t = blockIdx.x * blockDim.x + threadIdx.x;
    if (t >= n4) return;
    float4 v = *(const float4*)(x + (long long)t * 4);
    union { unsigned short us[4]; uint2 u2; } pk;
    pk.us[0] = f2bf(v.x); pk.us[1] = f2bf(v.y);
    pk.us[2] = f2bf(v.z); pk.us[3] = f2bf(v.w);
    *(uint2*)(xb + (long long)t * 4) = pk.u2;
}

// ---------------- CSR build (no fp atomics; parallel 3-kernel scan) -------
__global__ void count_deg(const int* __restrict__ dstv, int* __restrict__ deg, int E) {
    int e = blockIdx.x * blockDim.x + threadIdx.x;
    if (e < E) atomicAdd(&deg[dstv[e]], 1);
}

__global__ __launch_bounds__(256) void scan_blocks(const int* __restrict__ deg,
                                                   int* __restrict__ rowptr,
                                                   int* __restrict__ blocksum) {
    __shared__ int wtot[4];
    const int tid = threadIdx.x;
    const int lane = tid & 63;
    const int wave = tid >> 6;
    const int idx = blockIdx.x * SCAN_ELEMS + tid * 4;

    int4 d = make_int4(0, 0, 0, 0);
    if (idx < NNODES) d = *(const int4*)(deg + idx);
    int s = d.x + d.y + d.z + d.w;

    int inc = s;
    #pragma unroll
    for (int off = 1; off < 64; off <<= 1) {
        int n = __shfl_up(inc, off);
        if (lane >= off) inc += n;
    }
    if (lane == 63) wtot[wave] = inc;
    __syncthreads();
    int woff = 0;
    #pragma unroll
    for (int w = 0; w < 4; ++w) if (w < wave) woff += wtot[w];

    int excl = woff + inc - s;
    if (idx < NNODES) {
        int4 r;
        r.x = excl;
        r.y = r.x + d.x;
        r.z = r.y + d.y;
        r.w = r.z + d.z;
        *(int4*)(rowptr + idx) = r;
    }
    if (tid == 255) blocksum[blockIdx.x] = woff + inc;
}

__global__ __launch_bounds__(64) void scan_tops(const int* __restrict__ blocksum,
                                                int* __restrict__ blockoff,
                                                int* __restrict__ rowptr) {
    const int lane = threadIdx.x;
    int v = (lane < SCAN_BLK) ? blocksum[lane] : 0;
    int inc = v;
    #pragma unroll
    for (int off = 1; off < 64; off <<= 1) {
        int n = __shfl_up(inc, off);
        if (lane >= off) inc += n;
    }
    if (lane < SCAN_BLK) blockoff[lane] = inc - v;
    if (lane == 63) rowptr[NNODES] = inc;
}

__global__ __launch_bounds__(256) void scan_apply(int* __restrict__ rowptr,
                                                  int* __restrict__ cursor,
                                                  const int* __restrict__ blockoff) {
    const int idx = blockIdx.x * SCAN_ELEMS + threadIdx.x * 4;
    if (idx >= NNODES) return;
    const int off = blockoff[blockIdx.x];
    int4 r = *(const int4*)(rowptr + idx);
    r.x += off; r.y += off; r.z += off; r.w += off;
    *(int4*)(rowptr + idx) = r;
    *(int4*)(cursor + idx) = r;
}

__global__ void fill_csr(const int* __restrict__ srcv, const int* __restrict__ dstv,
                         int* __restrict__ cursor, int* __restrict__ srclist, int E) {
    int e = blockIdx.x * blockDim.x + threadIdx.x;
    if (e >= E) return;
    int pos = atomicAdd(&cursor[dstv[e]], 1);
    srclist[pos] = srcv[e];
}

// out[node] = xb[node] + sum_{e in CSR(node)} xb[srclist[e]]   (bf16 in, fp32 acc, bf16 out)
// One wave per node; 4 quarter-waves stream alternating edges; each lane owns
// 8 channels (uint4 = 16B). Quarters combined via shfl(lane^16), shfl(lane^32).
__global__ __launch_bounds__(256) void gather_sum_bf16(const unsigned short* __restrict__ xb,
                                                       const int* __restrict__ rowptr,
                                                       const int* __restrict__ srclist,
                                                       unsigned short* __restrict__ out) {
    int node = blockIdx.x * 4 + (threadIdx.x >> 6);
    if (node >= NNODES) return;
    const int lane = threadIdx.x & 63;
    const int q4 = lane >> 4;        // 0..3
    const int c = (lane & 15) * 8;   // channel base
    const int start = rowptr[node];
    const int end = rowptr[node + 1];

    float acc[8];
    if (q4 == 0) {   // self term (eps = 0)
        uint4 u = *(const uint4*)(xb + (long long)node * CH + c);
        acc[0] = bflo(u.x); acc[1] = bfhi(u.x);
        acc[2] = bflo(u.y); acc[3] = bfhi(u.y);
        acc[4] = bflo(u.z); acc[5] = bfhi(u.z);
        acc[6] = bflo(u.w); acc[7] = bfhi(u.w);
    } else {
        #pragma unroll
        for (int k = 0; k < 8; ++k) acc[k] = 0.f;
    }
    for (int i = start + q4; i < end; i += 4) {
        int s = srclist[i];
        uint4 u = *(const uint4*)(xb + (long long)s * CH + c);
        acc[0] += bflo(u.x); acc[1] += bfhi(u.x);
        acc[2] += bflo(u.y); acc[3] += bfhi(u.y);
        acc[4] += bflo(u.z); acc[5] += bfhi(u.z);
        acc[6] += bflo(u.w); acc[7] += bfhi(u.w);
    }
    #pragma unroll
    for (int k = 0; k < 8; ++k) {
        acc[k] += __shfl(acc[k], lane ^ 16);
        acc[k] += __shfl(acc[k], lane ^ 32);
    }
    if (q4 == 0) {
        uint4 o;
        o.x = (unsigned int)f2bf(acc[0]) | ((unsigned int)f2bf(acc[1]) << 16);
        o.y = (unsigned int)f2bf(acc[2]) | ((unsigned int)f2bf(acc[3]) << 16);
        o.z = (unsigned int)f2bf(acc[4]) | ((unsigned int)f2bf(acc[5]) << 16);
        o.w = (unsigned int)f2bf(acc[6]) | ((unsigned int)f2bf(acc[7]) << 16);
        *(uint4*)(out + (long long)node * CH + c) = o;
    }
}

// out[rows x ncols_out] = act( in @ wt^T + bias );  in is bf16 [rows][128]
template<int NTILES, bool RELU, bool OUTBF>
__global__ __launch_bounds__(256)
void gemm_kernel(const unsigned short* __restrict__ in,
                 const unsigned short* __restrict__ wt, const float* __restrict__ bias,
                 void* __restrict__ outp, int ncols_out) {
    __shared__ unsigned short Alds[64 * LDK];
    __shared__ unsigned short Wlds[NTILES * 16 * LDK];
    const int tid = threadIdx.x;
    const long long rowbase = (long long)blockIdx.x * 64;

    // stage A (64 x 128 bf16): 16 threads per row, uint4 each
    {
        int chunk = (tid & 15) * 8;
        #pragma unroll
        for (int r = tid >> 4; r < 64; r += 16) {
            *(uint4*)&Alds[r * LDK + chunk] = *(const uint4*)(in + (rowbase + r) * CH + chunk);
        }
    }
    // stage W (NTILES*16 x 128) bf16, already transposed/contiguous in ws
    {
        #pragma unroll
        for (int i = 0; i < NTILES; ++i) {
            int chunk = i * 256 + tid;
            int row = chunk >> 4;
            int col = (chunk & 15) * 8;
            *(uint4*)&Wlds[row * LDK + col] = *(const uint4*)(wt + row * CH + col);
        }
    }
    __syncthreads();

    const int wave = tid >> 6;
    const int lane = tid & 63;
    const int q = lane >> 4;
    const int ln = lane & 15;

    floatx4 acc[NTILES];
    #pragma unroll
    for (int t = 0; t < NTILES; ++t) acc[t] = (floatx4){0.f, 0.f, 0.f, 0.f};

    const int abase = (wave * 16 + ln) * LDK + q * 8;
    #pragma unroll
    for (int ks = 0; ks < 4; ++ks) {
        short8 af = *(const short8*)&Alds[abase + ks * 32];
        #pragma unroll
        for (int t = 0; t < NTILES; ++t) {
            short8 bf = *(const short8*)&Wlds[(t * 16 + ln) * LDK + q * 8 + ks * 32];
            acc[t] = __builtin_amdgcn_mfma_f32_16x16x32_bf16(af, bf, acc[t], 0, 0, 0);
        }
    }

    #pragma unroll
    for (int t = 0; t < NTILES; ++t) {
        int col = t * 16 + ln;
        if (col < ncols_out) {
            float b = bias[col];
            #pragma unroll
            for (int r = 0; r < 4; ++r) {
                long long row = rowbase + wave * 16 + q * 4 + r;
                float v = acc[t][r] + b;
                if (RELU) v = fmaxf(v, 0.f);
                if (OUTBF) ((unsigned short*)outp)[row * ncols_out + col] = f2bf(v);
                else       ((float*)outp)[row * ncols_out + col] = v;
            }
        }
    }
}

extern "C" void kernel_launch(void* const* d_in, const int* in_sizes, int n_in,
                              void* d_out, int out_size, void* d_ws, size_t ws_size,
                              hipStream_t stream) {
    const float* x    = (const float*)d_in[0];
    const int*   ei   = (const int*)d_in[1];
    const float* w1a  = (const float*)d_in[2];
    const float* b1a  = (const float*)d_in[3];
    const float* w1b  = (const float*)d_in[4];
    const float* b1b  = (const float*)d_in[5];
    const float* w2a  = (const float*)d_in[6];
    const float* b2a  = (const float*)d_in[7];
    const float* w2b  = (const float*)d_in[8];
    const float* b2b  = (const float*)d_in[9];
    const float* wlin = (const float*)d_in[10];
    const float* blin = (const float*)d_in[11];
    const int E = in_sizes[1] / 2;
    const int* srcv = ei;
    const int* dstv = ei + E;

    const size_t NODEF = (size_t)NNODES * CH;                    // 5.12M elems
    unsigned short* wt  = (unsigned short*)d_ws;                 // 143 KB, pad to 256 KB
    unsigned short* xb   = (unsigned short*)((char*)d_ws + 262144);
    unsigned short* bufA = xb + NODEF;
    unsigned short* bufB = bufA + NODEF;
    unsigned short* bufC = bufB + NODEF;
    int* rowptr   = (int*)(bufC + NODEF);                        // NNODES+1
    int* srclist  = rowptr + (NNODES + 1);                       // E
    int* blocksum = srclist + E;                                 // pad 64
    int* blockoff = blocksum + 64;
    int* deg      = blockoff + 64;
    int* cursor   = deg + NNODES;

    const int WT_ELEMS = 4 * CH * CH + 48 * CH;
    prep_weights<<<(WT_ELEMS + 255) / 256, 256, 0, stream>>>(w1a, w1b, w2a, w2b, wlin, wt);
    cvt_bf16<<<(int)(NODEF / 4 + 255) / 256, 256, 0, stream>>>(x, xb, (int)(NODEF / 4));

    // ---- CSR build ----
    hipMemsetAsync(deg, 0, NNODES * sizeof(int), stream);
    count_deg<<<(E + 255) / 256, 256, 0, stream>>>(dstv, deg, E);
    scan_blocks<<<SCAN_BLK, 256, 0, stream>>>(deg, rowptr, blocksum);
    scan_tops<<<1, 64, 0, stream>>>(blocksum, blockoff, rowptr);
    scan_apply<<<SCAN_BLK, 256, 0, stream>>>(rowptr, cursor, blockoff);
    fill_csr<<<(E + 255) / 256, 256, 0, stream>>>(srcv, dstv, cursor, srclist, E);

    const int GBLOCKS = (NNODES + 3) / 4;
    const int M = CH * CH;

    // ---- layer 1 ----
    gather_sum_bf16<<<GBLOCKS, 256, 0, stream>>>(xb, rowptr, srclist, bufA);     // bufA = x + agg(x)
    gemm_kernel<8, true, true ><<<NNODES / 64, 256, 0, stream>>>(bufA, wt,         b1a, bufB, CH);
    gemm_kernel<8, true, true ><<<NNODES / 64, 256, 0, stream>>>(bufB, wt + M,     b1b, bufC, CH);   // bufC = h1
    // ---- layer 2 ----
    gather_sum_bf16<<<GBLOCKS, 256, 0, stream>>>(bufC, rowptr, srclist, bufA);   // bufA = h1 + agg(h1)
    gemm_kernel<8, true, true ><<<NNODES / 64, 256, 0, stream>>>(bufA, wt + 2 * M, b2a, bufB, CH);
    gemm_kernel<8, true, true ><<<NNODES / 64, 256, 0, stream>>>(bufB, wt + 3 * M, b2b, bufA, CH);   // bufA = h2
    // ---- final linear ----
    gemm_kernel<3, false, false><<<NNODES / 64, 256, 0, stream>>>(bufA, wt + 4 * M, blin, d_out, NCLS);
}